// Round 3
// baseline (3002.208 us; speedup 1.0000x reference)
//
#include <hip/hip_runtime.h>
#include <cstdint>
#include <cstddef>

#define EMB    512
#define HID    512
#define NCLASS 50257
#define BATCH  64
#define STEPS  256
#define FOURH  2048

typedef __attribute__((ext_vector_type(8))) short    bf16x8;
typedef __attribute__((ext_vector_type(4))) float    f32x4;
typedef __attribute__((ext_vector_type(8))) _Float16 h8v;

__device__ __forceinline__ unsigned short f2bf(float f) {
    union { float f; unsigned int u; } v; v.f = f;
    unsigned int u = v.u;
    return (unsigned short)((u + 0x7fffu + ((u >> 16) & 1u)) >> 16);
}

// ---------------- prep kernels ----------------

__global__ void k_bias(const float* __restrict__ bi, const float* __restrict__ bh,
                       float* __restrict__ bias) {
    int i = blockIdx.x * 256 + threadIdx.x;
    if (i < FOURH) bias[i] = bi[i] + bh[i];
}

// Wi [512][2048] fp32 -> WiT [2048][512] bf16
__global__ void k_wit(const float* __restrict__ Wi, unsigned short* __restrict__ WiT) {
    int n = blockIdx.x;
    int l = threadIdx.x;
    int k0 = l * 8;
    unsigned short t[8];
#pragma unroll
    for (int i = 0; i < 8; i++)
        t[i] = f2bf(Wi[(size_t)(k0 + i) * FOURH + n]);
    uint4 v;
    v.x = (unsigned)t[0] | ((unsigned)t[1] << 16);
    v.y = (unsigned)t[2] | ((unsigned)t[3] << 16);
    v.z = (unsigned)t[4] | ((unsigned)t[5] << 16);
    v.w = (unsigned)t[6] | ((unsigned)t[7] << 16);
    *(uint4*)(WiT + (size_t)n * EMB + k0) = v;
}

// Wh [512][2048] fp32 -> WhP [64 bid][32 c][512 k] fp16
// packed col c <-> (unit_local = (c>>4)*4 + ((c>>2)&3), gate = c&3)
// so lane (ct,quad) acc regs r=0..3 are gates i,f,g,o of unit ct*4+quad.
__global__ void k_whP(const float* __restrict__ Wh, _Float16* __restrict__ WhP) {
    int idx = blockIdx.x;            // 0..2047 = bid*32 + c
    int bidb = idx >> 5, c = idx & 31;
    int ul   = ((c >> 4) << 2) + ((c >> 2) & 3);
    int gate = c & 3;
    int gcol = gate * 512 + bidb * 8 + ul;
    int k0 = threadIdx.x * 8;
    h8v r;
#pragma unroll
    for (int i = 0; i < 8; i++)
        r[i] = (_Float16)Wh[(size_t)(k0 + i) * FOURH + gcol];
    *(h8v*)(WhP + (size_t)idx * 512 + k0) = r;
}

// XA[m][k] = bf16(emb[X[b][t]][k]),  m = t*64 + b
__global__ void k_gather(const int* __restrict__ X, const float* __restrict__ emb,
                         unsigned short* __restrict__ XA) {
    int chunk = blockIdx.x * 256 + threadIdx.x;
    int m  = chunk >> 6;
    int c8 = (chunk & 63) * 8;
    int t = m >> 6, b = m & 63;
    int row = X[b * STEPS + t];
    const float4* src = (const float4*)(emb + (size_t)row * EMB + c8);
    float4 f0 = src[0], f1 = src[1];
    uint4 v;
    v.x = (unsigned)f2bf(f0.x) | ((unsigned)f2bf(f0.y) << 16);
    v.y = (unsigned)f2bf(f0.z) | ((unsigned)f2bf(f0.w) << 16);
    v.z = (unsigned)f2bf(f1.x) | ((unsigned)f2bf(f1.y) << 16);
    v.w = (unsigned)f2bf(f1.z) | ((unsigned)f2bf(f1.w) << 16);
    *(uint4*)(XA + (size_t)m * EMB + c8) = v;
}

__global__ void k_zero(int* __restrict__ p, int n) {
    int i = blockIdx.x * 256 + threadIdx.x;
    if (i < n) p[i] = 0;
}

// ---------------- K1: XWT[t][col][b] = (XA @ Wi)^T + (bi+bh) ----------------
__global__ __launch_bounds__(256) void k_gemm1(const unsigned short* __restrict__ XA,
                                               const unsigned short* __restrict__ WiT,
                                               const float* __restrict__ bias,
                                               float* __restrict__ XWT) {
    __shared__ unsigned short Al[64 * 48];
    __shared__ unsigned short Bl[64 * 48];
    const int t  = blockIdx.y;
    const int m0 = t * 64;
    const int n0 = blockIdx.x * 64;
    const int tid  = threadIdx.x;
    const int w    = tid >> 6;
    const int lane = tid & 63;
    const int quad = lane >> 4;
    const int l16  = lane & 15;
    const int ar = tid >> 2;
    const int ac = (tid & 3) * 8;

    f32x4 acc[4];
#pragma unroll
    for (int i = 0; i < 4; i++) acc[i] = (f32x4){0.f, 0.f, 0.f, 0.f};

    for (int kk = 0; kk < 16; kk++) {
        const int k0 = kk * 32;
        __syncthreads();
        *(uint4*)(&Al[ar * 48 + ac]) = *(const uint4*)(XA  + (size_t)(m0 + ar) * EMB + k0 + ac);
        *(uint4*)(&Bl[ar * 48 + ac]) = *(const uint4*)(WiT + (size_t)(n0 + ar) * EMB + k0 + ac);
        __syncthreads();
        bf16x8 afrag = *(const bf16x8*)(&Bl[(w * 16 + l16) * 48 + quad * 8]);
#pragma unroll
        for (int mt = 0; mt < 4; mt++) {
            bf16x8 bfrag = *(const bf16x8*)(&Al[(mt * 16 + l16) * 48 + quad * 8]);
            acc[mt] = __builtin_amdgcn_mfma_f32_16x16x32_bf16(afrag, bfrag, acc[mt], 0, 0, 0);
        }
    }
    float bv[4];
#pragma unroll
    for (int r = 0; r < 4; r++) bv[r] = bias[n0 + w * 16 + quad * 4 + r];
#pragma unroll
    for (int mt = 0; mt < 4; mt++)
#pragma unroll
        for (int r = 0; r < 4; r++)
            XWT[((size_t)t * FOURH + n0 + w * 16 + quad * 4 + r) * 64 + mt * 16 + l16]
                = acc[mt][r] + bv[r];
}

// ---------------- K2: persistent LSTM recurrence (plain launch + flag barrier) --
// 64 blocks x 512 thr, all trivially co-resident on 256 CUs. Block owns units
// bid*8..bid*8+7 (32 packed gate cols). Wave wid -> (ct=wid>>2, bt=wid&3).
// Lane (quad,l16): unit u=ct*4+quad, batch b=bt*16+l16; acc regs = i,f,g,o.
// c-state in 1 VGPR across all 256 steps; Wh in 16 persistent A-frags (64 VGPR).
// Barrier: per-block monotonic flags (64B apart). Writer: wave0 stores 1KB h
// granule -> __threadfence (agent release) -> lane0 release-stores flags[bid]=t+1.
// Waiter: wave0 acquire-polls all 64 flags (invalidates L1 -> no stale h),
// then __syncthreads releases waves 1-7. Double-buffer is race-free: flag t+1
// implies that block consumed h(t), and buffer t&1 is only rewritten at t+1
// after ALL flags >= t+1.
__global__ __launch_bounds__(512, 1) void k_rnn(const float* __restrict__ XWT,
                                                const _Float16* __restrict__ WhP,
                                                _Float16* __restrict__ hG,
                                                float* __restrict__ hfinal,
                                                unsigned int* __restrict__ flags) {
    __shared__ _Float16 hw[64 * 8];   // gather of this block's h slice

    const int tid  = threadIdx.x;
    const int bid  = blockIdx.x;
    const int lane = tid & 63;
    const int wid  = tid >> 6;
    const int quad = lane >> 4;
    const int l16  = lane & 15;
    const int ct   = wid >> 2;
    const int bt   = wid & 3;
    const int u    = ct * 4 + quad;       // unit-local 0..7
    const int b    = bt * 16 + l16;       // batch 0..63

    // persistent Wh A-fragments: lane holds WhP[bid][ct*16+l16][kk*32+quad*8 ..+7]
    h8v afrag[16];
    const _Float16* wsrc = WhP + ((size_t)(bid * 32 + ct * 16 + l16)) * 512 + quad * 8;
#pragma unroll
    for (int kk = 0; kk < 16; kk++) afrag[kk] = *(const h8v*)(wsrc + kk * 32);

    float c_state = 0.f;
    const size_t xwoff = (size_t)(bid * 8 + u) * 64 + b;

    // preload xw for t=0
    float xw0, xw1, xw2, xw3;
    {
        const float* xp = XWT + xwoff;
        xw0 = xp[0 * 32768]; xw1 = xp[1 * 32768];
        xw2 = xp[2 * 32768]; xw3 = xp[3 * 32768];
    }

    for (int t = 0; t < STEPS; t++) {
        // B-fragment base: row b of h(t), k-byte offset quad*16
        const char* hsrc = (const char*)hG + (size_t)(t & 1) * 65536
                         + (size_t)b * 1024 + quad * 16;

        f32x4 acc0 = {0.f, 0.f, 0.f, 0.f};
        f32x4 acc1 = {0.f, 0.f, 0.f, 0.f};
#pragma unroll
        for (int kk = 0; kk < 16; kk += 2) {
            h8v b0 = *(const h8v*)(hsrc + kk * 64);
            h8v b1 = *(const h8v*)(hsrc + (kk + 1) * 64);
            acc0 = __builtin_amdgcn_mfma_f32_16x16x32_f16(afrag[kk],     b0, acc0, 0, 0, 0);
            acc1 = __builtin_amdgcn_mfma_f32_16x16x32_f16(afrag[kk + 1], b1, acc1, 0, 0, 0);
        }
        f32x4 acc = acc0 + acc1;

        float pre0 = acc[0] + xw0;
        float pre1 = acc[1] + xw1;
        float pre2 = acc[2] + xw2;
        float pre3 = acc[3] + xw3;
        float is = 1.f / (1.f + __expf(-pre0));
        float fs = 1.f / (1.f + __expf(-pre1));
        float gt = tanhf(pre2);
        float os = 1.f / (1.f + __expf(-pre3));
        c_state = fs * c_state + is * gt;
        float hnew = os * tanhf(c_state);

        if (t == STEPS - 1) {
            hfinal[(size_t)b * HID + bid * 8 + u] = hnew;
            break;   // uniform exit; kernel boundary publishes hfinal to k_out
        }

        hw[b * 8 + u] = (_Float16)hnew;
        __syncthreads();
        if (tid < 64) {   // wave0: batch = tid, 16B granule at unit-col bid*8
            uint4 v = *(const uint4*)(hw + tid * 8);
            *(uint4*)((char*)hG + (size_t)((t + 1) & 1) * 65536
                      + (size_t)tid * 1024 + bid * 16) = v;
            __threadfence();   // agent-scope release: h granule visible before flag
        }
        __syncthreads();
        if (tid == 0)
            __hip_atomic_store(&flags[bid * 16], (unsigned)(t + 1),
                               __ATOMIC_RELEASE, __HIP_MEMORY_SCOPE_AGENT);

        // prefetch xw(t+1): issued before the spin so it completes under it
        {
            const float* xp = XWT + (size_t)(t + 1) * FOURH * 64 + xwoff;
            xw0 = xp[0 * 32768]; xw1 = xp[1 * 32768];
            xw2 = xp[2 * 32768]; xw3 = xp[3 * 32768];
        }

        if (tid < 64) {   // wave0 polls; acquire load invalidates L1 each pass
            const unsigned tgt = (unsigned)(t + 1);
            unsigned guard = 0;
            unsigned v = __hip_atomic_load(&flags[lane * 16],
                                           __ATOMIC_ACQUIRE, __HIP_MEMORY_SCOPE_AGENT);
            while (!__all(v >= tgt)) {
                __builtin_amdgcn_s_sleep(1);
                if (++guard > (1u << 17)) break;   // bailout: wrong answer, not a hang
                v = __hip_atomic_load(&flags[lane * 16],
                                      __ATOMIC_ACQUIRE, __HIP_MEMORY_SCOPE_AGENT);
            }
        }
        __syncthreads();   // releases waves 1-7 with h(t+1) visible
    }
}

// ---------------- K3: out = h @ Wout^T + bout ----------------
__global__ __launch_bounds__(128) void k_out(const float* __restrict__ Wout,
                                             const float* __restrict__ bout,
                                             const float* __restrict__ hfinal,
                                             float* __restrict__ out) {
    __shared__ float hl[BATCH * 128];
    const int tid = threadIdx.x;
    const int n = blockIdx.x * 128 + tid;
    const bool valid = n < NCLASS;
    float acc[BATCH];
#pragma unroll
    for (int b = 0; b < BATCH; b++) acc[b] = 0.f;
    const float4* W4 = (const float4*)Wout;
    const float4* h4 = (const float4*)hfinal;
    float4* hl4 = (float4*)hl;

    for (int kq = 0; kq < 4; kq++) {
        __syncthreads();
#pragma unroll
        for (int i = 0; i < 16; i++) {
            int f = i * 128 + tid;
            int b = f >> 5, kk = f & 31;
            hl4[f] = h4[b * 128 + kq * 32 + kk];
        }
        __syncthreads();
        if (valid) {
            for (int kk = 0; kk < 32; kk++) {
                float4 wv = W4[(size_t)n * 128 + kq * 32 + kk];
#pragma unroll
                for (int b = 0; b < BATCH; b++) {
                    float4 hv = hl4[b * 32 + kk];
                    acc[b] = fmaf(wv.x, hv.x, acc[b]);
                    acc[b] = fmaf(wv.y, hv.y, acc[b]);
                    acc[b] = fmaf(wv.z, hv.z, acc[b]);
                    acc[b] = fmaf(wv.w, hv.w, acc[b]);
                }
            }
        }
    }
    if (valid) {
        float bv = bout[n];
        for (int b = 0; b < BATCH; b++)
            out[(size_t)b * NCLASS + n] = acc[b] + bv;
    }
}

// ---------------- launch ----------------

extern "C" void kernel_launch(void* const* d_in, const int* in_sizes, int n_in,
                              void* d_out, int out_size, void* d_ws, size_t ws_size,
                              hipStream_t stream) {
    const int*   X    = (const int*)  d_in[0];
    const float* emb  = (const float*)d_in[1];
    const float* Wi   = (const float*)d_in[2];
    const float* Wh   = (const float*)d_in[3];
    const float* bi   = (const float*)d_in[4];
    const float* bh   = (const float*)d_in[5];
    const float* Wout = (const float*)d_in[10];
    const float* bout = (const float*)d_in[11];
    float* out = (float*)d_out;

    char* w = (char*)d_ws;
    float*          XWT    = (float*)(w);                           // 134217728 B
    unsigned short* XA     = (unsigned short*)(w + 134217728);      //  16777216 B (K1 only)
    // hG/flags aliased into XA tail — zeroed AFTER k_gemm1 consumed XA:
    _Float16*       hG     = (_Float16*)(w + 150732800);            //    131072 B (2 bufs)
    unsigned int*   flags  = (unsigned int*)(w + 150863872);        //      4096 B (64 x 64B)
    unsigned short* WiT    = (unsigned short*)(w + 150994944);      //   2097152 B
    _Float16*       WhP    = (_Float16*)(w + 153092096);            //   2097152 B
    float*          bias   = (float*)(w + 155189248);               //      8192 B
    float*          hfinal = (float*)(w + 155197440);               //    131072 B

    k_bias  <<<8,    256, 0, stream>>>(bi, bh, bias);
    k_wit   <<<2048,  64, 0, stream>>>(Wi, WiT);
    k_whP   <<<2048,  64, 0, stream>>>(Wh, WhP);
    k_gather<<<4096, 256, 0, stream>>>(X, emb, XA);
    k_gemm1 <<<dim3(32, 256), 256, 0, stream>>>(XA, WiT, bias, XWT);
    k_zero  <<<132,  256, 0, stream>>>((int*)hG, 33792);            // hG both bufs + flags

    k_rnn   <<<64,   512, 0, stream>>>(XWT, WhP, hG, hfinal, flags);

    k_out   <<<393,  128, 0, stream>>>(Wout, bout, hfinal, out);
}

// Round 4
// 2192.830 us; speedup vs baseline: 1.3691x; 1.3691x over previous
//
#include <hip/hip_runtime.h>
#include <cstdint>
#include <cstddef>

#define EMB    512
#define HID    512
#define NCLASS 50257
#define BATCH  64
#define STEPS  256
#define FOURH  2048

typedef __attribute__((ext_vector_type(8))) short    bf16x8;
typedef __attribute__((ext_vector_type(4))) float    f32x4;
typedef __attribute__((ext_vector_type(8))) _Float16 h8v;

__device__ __forceinline__ unsigned short f2bf(float f) {
    union { float f; unsigned int u; } v; v.f = f;
    unsigned int u = v.u;
    return (unsigned short)((u + 0x7fffu + ((u >> 16) & 1u)) >> 16);
}

// ---------------- prep kernels ----------------

__global__ void k_bias(const float* __restrict__ bi, const float* __restrict__ bh,
                       float* __restrict__ bias) {
    int i = blockIdx.x * 256 + threadIdx.x;
    if (i < FOURH) bias[i] = bi[i] + bh[i];
}

// Wi [512][2048] fp32 -> WiT [2048][512] bf16
__global__ void k_wit(const float* __restrict__ Wi, unsigned short* __restrict__ WiT) {
    int n = blockIdx.x;
    int l = threadIdx.x;
    int k0 = l * 8;
    unsigned short t[8];
#pragma unroll
    for (int i = 0; i < 8; i++)
        t[i] = f2bf(Wi[(size_t)(k0 + i) * FOURH + n]);
    uint4 v;
    v.x = (unsigned)t[0] | ((unsigned)t[1] << 16);
    v.y = (unsigned)t[2] | ((unsigned)t[3] << 16);
    v.z = (unsigned)t[4] | ((unsigned)t[5] << 16);
    v.w = (unsigned)t[6] | ((unsigned)t[7] << 16);
    *(uint4*)(WiT + (size_t)n * EMB + k0) = v;
}

// Wh [512][2048] fp32 -> WhP [64 bid][32 c][512 k] fp16
// packed col c <-> (unit_local = (c>>4)*4 + ((c>>2)&3), gate = c&3)
// so lane (ct,quad) acc regs r=0..3 are gates i,f,g,o of unit ct*4+quad.
__global__ void k_whP(const float* __restrict__ Wh, _Float16* __restrict__ WhP) {
    int idx = blockIdx.x;            // 0..2047 = bid*32 + c
    int bidb = idx >> 5, c = idx & 31;
    int ul   = ((c >> 4) << 2) + ((c >> 2) & 3);
    int gate = c & 3;
    int gcol = gate * 512 + bidb * 8 + ul;
    int k0 = threadIdx.x * 8;
    h8v r;
#pragma unroll
    for (int i = 0; i < 8; i++)
        r[i] = (_Float16)Wh[(size_t)(k0 + i) * FOURH + gcol];
    *(h8v*)(WhP + (size_t)idx * 512 + k0) = r;
}

// XA[m][k] = bf16(emb[X[b][t]][k]),  m = t*64 + b
__global__ void k_gather(const int* __restrict__ X, const float* __restrict__ emb,
                         unsigned short* __restrict__ XA) {
    int chunk = blockIdx.x * 256 + threadIdx.x;
    int m  = chunk >> 6;
    int c8 = (chunk & 63) * 8;
    int t = m >> 6, b = m & 63;
    int row = X[b * STEPS + t];
    const float4* src = (const float4*)(emb + (size_t)row * EMB + c8);
    float4 f0 = src[0], f1 = src[1];
    uint4 v;
    v.x = (unsigned)f2bf(f0.x) | ((unsigned)f2bf(f0.y) << 16);
    v.y = (unsigned)f2bf(f0.z) | ((unsigned)f2bf(f0.w) << 16);
    v.z = (unsigned)f2bf(f1.x) | ((unsigned)f2bf(f1.y) << 16);
    v.w = (unsigned)f2bf(f1.z) | ((unsigned)f2bf(f1.w) << 16);
    *(uint4*)(XA + (size_t)m * EMB + c8) = v;
}

__global__ void k_zero(int* __restrict__ p, int n) {
    int i = blockIdx.x * 256 + threadIdx.x;
    if (i < n) p[i] = 0;
}

// ---------------- K1: XWT[t][col][b] = (XA @ Wi)^T + (bi+bh) ----------------
__global__ __launch_bounds__(256) void k_gemm1(const unsigned short* __restrict__ XA,
                                               const unsigned short* __restrict__ WiT,
                                               const float* __restrict__ bias,
                                               float* __restrict__ XWT) {
    __shared__ unsigned short Al[64 * 48];
    __shared__ unsigned short Bl[64 * 48];
    const int t  = blockIdx.y;
    const int m0 = t * 64;
    const int n0 = blockIdx.x * 64;
    const int tid  = threadIdx.x;
    const int w    = tid >> 6;
    const int lane = tid & 63;
    const int quad = lane >> 4;
    const int l16  = lane & 15;
    const int ar = tid >> 2;
    const int ac = (tid & 3) * 8;

    f32x4 acc[4];
#pragma unroll
    for (int i = 0; i < 4; i++) acc[i] = (f32x4){0.f, 0.f, 0.f, 0.f};

    for (int kk = 0; kk < 16; kk++) {
        const int k0 = kk * 32;
        __syncthreads();
        *(uint4*)(&Al[ar * 48 + ac]) = *(const uint4*)(XA  + (size_t)(m0 + ar) * EMB + k0 + ac);
        *(uint4*)(&Bl[ar * 48 + ac]) = *(const uint4*)(WiT + (size_t)(n0 + ar) * EMB + k0 + ac);
        __syncthreads();
        bf16x8 afrag = *(const bf16x8*)(&Bl[(w * 16 + l16) * 48 + quad * 8]);
#pragma unroll
        for (int mt = 0; mt < 4; mt++) {
            bf16x8 bfrag = *(const bf16x8*)(&Al[(mt * 16 + l16) * 48 + quad * 8]);
            acc[mt] = __builtin_amdgcn_mfma_f32_16x16x32_bf16(afrag, bfrag, acc[mt], 0, 0, 0);
        }
    }
    float bv[4];
#pragma unroll
    for (int r = 0; r < 4; r++) bv[r] = bias[n0 + w * 16 + quad * 4 + r];
#pragma unroll
    for (int mt = 0; mt < 4; mt++)
#pragma unroll
        for (int r = 0; r < 4; r++)
            XWT[((size_t)t * FOURH + n0 + w * 16 + quad * 4 + r) * 64 + mt * 16 + l16]
                = acc[mt][r] + bv[r];
}

// ---------------- K2: persistent LSTM recurrence, MALL-coherent barrier --------
// 64 blocks x 512 thr. Block owns units bid*8..bid*8+7 (32 packed gate cols).
// Lane (quad,l16) of wave (ct,bt): unit u=ct*4+quad, batch b=bt*16+l16;
// acc regs = i,f,g,o. c-state in 1 VGPR; Wh in 16 persistent A-frags.
// Sync protocol (no cache-maintenance fences — round-3 post-mortem showed
// the release-wbl2 + per-poll-inv were the 9.6us/step cost):
//   writer: h granule as relaxed agent-scope 8B atomic stores (write-through
//           to MALL, no dirty L2) -> wave-local s_waitcnt vmcnt(0) -> relaxed
//           flag store (ordered: h already globally visible when acked).
//   reader: spin on RELAXED agent-scope flag loads (scope bypasses L1/L2,
//           no inv per poll); after spin, ONE acquire load -> single L1/L2
//           invalidate so the plain 16B MFMA h-loads see MALL-fresh data.
// Race-freedom: a block raises flag t+1 only after its step-t h-loads have
// RETURNED (consumed via syncthreads before the gather), so in-flight stale
// reads cannot be overtaken; buffer (t+1)&1 is rewritten only after all
// flags >= t+1, i.e. after every block finished reading it at step t-1.
__global__ __launch_bounds__(512, 1) void k_rnn(const float* __restrict__ XWT,
                                                const _Float16* __restrict__ WhP,
                                                _Float16* __restrict__ hG,
                                                float* __restrict__ hfinal,
                                                unsigned int* __restrict__ flags) {
    __shared__ _Float16 hw[64 * 8];   // gather of this block's h slice

    const int tid  = threadIdx.x;
    const int bid  = blockIdx.x;
    const int lane = tid & 63;
    const int wid  = tid >> 6;
    const int quad = lane >> 4;
    const int l16  = lane & 15;
    const int ct   = wid >> 2;
    const int bt   = wid & 3;
    const int u    = ct * 4 + quad;       // unit-local 0..7
    const int b    = bt * 16 + l16;       // batch 0..63

    // persistent Wh A-fragments: lane holds WhP[bid][ct*16+l16][kk*32+quad*8 ..+7]
    h8v afrag[16];
    const _Float16* wsrc = WhP + ((size_t)(bid * 32 + ct * 16 + l16)) * 512 + quad * 8;
#pragma unroll
    for (int kk = 0; kk < 16; kk++) afrag[kk] = *(const h8v*)(wsrc + kk * 32);

    float c_state = 0.f;
    const size_t xwoff = (size_t)(bid * 8 + u) * 64 + b;

    // preload xw for t=0
    float xw0, xw1, xw2, xw3;
    {
        const float* xp = XWT + xwoff;
        xw0 = xp[0 * 32768]; xw1 = xp[1 * 32768];
        xw2 = xp[2 * 32768]; xw3 = xp[3 * 32768];
    }

    for (int t = 0; t < STEPS; t++) {
        // B-fragment base: row b of h(t), k-byte offset quad*16
        const char* hsrc = (const char*)hG + (size_t)(t & 1) * 65536
                         + (size_t)b * 1024 + quad * 16;

        f32x4 acc0 = {0.f, 0.f, 0.f, 0.f};
        f32x4 acc1 = {0.f, 0.f, 0.f, 0.f};
#pragma unroll
        for (int kk = 0; kk < 16; kk += 2) {
            h8v b0 = *(const h8v*)(hsrc + kk * 64);
            h8v b1 = *(const h8v*)(hsrc + (kk + 1) * 64);
            acc0 = __builtin_amdgcn_mfma_f32_16x16x32_f16(afrag[kk],     b0, acc0, 0, 0, 0);
            acc1 = __builtin_amdgcn_mfma_f32_16x16x32_f16(afrag[kk + 1], b1, acc1, 0, 0, 0);
        }
        f32x4 acc = acc0 + acc1;

        float pre0 = acc[0] + xw0;
        float pre1 = acc[1] + xw1;
        float pre2 = acc[2] + xw2;
        float pre3 = acc[3] + xw3;
        float is = 1.f / (1.f + __expf(-pre0));
        float fs = 1.f / (1.f + __expf(-pre1));
        float gt = tanhf(pre2);
        float os = 1.f / (1.f + __expf(-pre3));
        c_state = fs * c_state + is * gt;
        float hnew = os * tanhf(c_state);

        if (t == STEPS - 1) {
            hfinal[(size_t)b * HID + bid * 8 + u] = hnew;
            break;   // uniform exit; kernel boundary publishes hfinal to k_out
        }

        hw[b * 8 + u] = (_Float16)hnew;
        __syncthreads();   // also guarantees all waves' h(t) loads have returned
        if (tid < 64) {    // wave0: batch = tid, 16B granule at unit-col bid*8
            const unsigned long long* src = (const unsigned long long*)(hw + tid * 8);
            unsigned long long lo = src[0], hi = src[1];
            unsigned long long* dst = (unsigned long long*)((char*)hG
                + (size_t)((t + 1) & 1) * 65536 + (size_t)tid * 1024 + bid * 16);
            __hip_atomic_store(dst,     lo, __ATOMIC_RELAXED, __HIP_MEMORY_SCOPE_AGENT);
            __hip_atomic_store(dst + 1, hi, __ATOMIC_RELAXED, __HIP_MEMORY_SCOPE_AGENT);
            asm volatile("s_waitcnt vmcnt(0)" ::: "memory");   // h acked at MALL
            if (tid == 0)
                __hip_atomic_store(&flags[bid * 16], (unsigned)(t + 1),
                                   __ATOMIC_RELAXED, __HIP_MEMORY_SCOPE_AGENT);
        }

        // prefetch xw(t+1): plain loads, complete under the spin
        {
            const float* xp = XWT + (size_t)(t + 1) * FOURH * 64 + xwoff;
            xw0 = xp[0 * 32768]; xw1 = xp[1 * 32768];
            xw2 = xp[2 * 32768]; xw3 = xp[3 * 32768];
        }

        if (tid < 64) {   // wave0 polls relaxed (no cache ops per iteration)
            const unsigned tgt = (unsigned)(t + 1);
            unsigned guard = 0;
            unsigned v = __hip_atomic_load(&flags[lane * 16],
                                           __ATOMIC_RELAXED, __HIP_MEMORY_SCOPE_AGENT);
            while (!__all(v >= tgt)) {
                __builtin_amdgcn_s_sleep(1);
                if (++guard > (1u << 17)) break;   // bailout: wrong answer, not a hang
                v = __hip_atomic_load(&flags[lane * 16],
                                      __ATOMIC_RELAXED, __HIP_MEMORY_SCOPE_AGENT);
            }
            // ONE acquire per step: L1/L2 invalidate so plain h loads read fresh
            (void)__hip_atomic_load(&flags[0], __ATOMIC_ACQUIRE,
                                    __HIP_MEMORY_SCOPE_AGENT);
        }
        __syncthreads();   // releases waves 1-7 with h(t+1) visible
    }
}

// ---------------- K3: out = h @ Wout^T + bout ----------------
__global__ __launch_bounds__(128) void k_out(const float* __restrict__ Wout,
                                             const float* __restrict__ bout,
                                             const float* __restrict__ hfinal,
                                             float* __restrict__ out) {
    __shared__ float hl[BATCH * 128];
    const int tid = threadIdx.x;
    const int n = blockIdx.x * 128 + tid;
    const bool valid = n < NCLASS;
    float acc[BATCH];
#pragma unroll
    for (int b = 0; b < BATCH; b++) acc[b] = 0.f;
    const float4* W4 = (const float4*)Wout;
    const float4* h4 = (const float4*)hfinal;
    float4* hl4 = (float4*)hl;

    for (int kq = 0; kq < 4; kq++) {
        __syncthreads();
#pragma unroll
        for (int i = 0; i < 16; i++) {
            int f = i * 128 + tid;
            int b = f >> 5, kk = f & 31;
            hl4[f] = h4[b * 128 + kq * 32 + kk];
        }
        __syncthreads();
        if (valid) {
            for (int kk = 0; kk < 32; kk++) {
                float4 wv = W4[(size_t)n * 128 + kq * 32 + kk];
#pragma unroll
                for (int b = 0; b < BATCH; b++) {
                    float4 hv = hl4[b * 32 + kk];
                    acc[b] = fmaf(wv.x, hv.x, acc[b]);
                    acc[b] = fmaf(wv.y, hv.y, acc[b]);
                    acc[b] = fmaf(wv.z, hv.z, acc[b]);
                    acc[b] = fmaf(wv.w, hv.w, acc[b]);
                }
            }
        }
    }
    if (valid) {
        float bv = bout[n];
        for (int b = 0; b < BATCH; b++)
            out[(size_t)b * NCLASS + n] = acc[b] + bv;
    }
}

// ---------------- launch ----------------

extern "C" void kernel_launch(void* const* d_in, const int* in_sizes, int n_in,
                              void* d_out, int out_size, void* d_ws, size_t ws_size,
                              hipStream_t stream) {
    const int*   X    = (const int*)  d_in[0];
    const float* emb  = (const float*)d_in[1];
    const float* Wi   = (const float*)d_in[2];
    const float* Wh   = (const float*)d_in[3];
    const float* bi   = (const float*)d_in[4];
    const float* bh   = (const float*)d_in[5];
    const float* Wout = (const float*)d_in[10];
    const float* bout = (const float*)d_in[11];
    float* out = (float*)d_out;

    char* w = (char*)d_ws;
    float*          XWT    = (float*)(w);                           // 134217728 B
    unsigned short* XA     = (unsigned short*)(w + 134217728);      //  16777216 B (K1 only)
    // hG/flags aliased into XA tail — zeroed AFTER k_gemm1 consumed XA:
    _Float16*       hG     = (_Float16*)(w + 150732800);            //    131072 B (2 bufs)
    unsigned int*   flags  = (unsigned int*)(w + 150863872);        //      4096 B (64 x 64B)
    unsigned short* WiT    = (unsigned short*)(w + 150994944);      //   2097152 B
    _Float16*       WhP    = (_Float16*)(w + 153092096);            //   2097152 B
    float*          bias   = (float*)(w + 155189248);               //      8192 B
    float*          hfinal = (float*)(w + 155197440);               //    131072 B

    k_bias  <<<8,    256, 0, stream>>>(bi, bh, bias);
    k_wit   <<<2048,  64, 0, stream>>>(Wi, WiT);
    k_whP   <<<2048,  64, 0, stream>>>(Wh, WhP);
    k_gather<<<4096, 256, 0, stream>>>(X, emb, XA);
    k_gemm1 <<<dim3(32, 256), 256, 0, stream>>>(XA, WiT, bias, XWT);
    k_zero  <<<132,  256, 0, stream>>>((int*)hG, 33792);            // hG both bufs + flags

    k_rnn   <<<64,   512, 0, stream>>>(XWT, WhP, hG, hfinal, flags);

    k_out   <<<393,  128, 0, stream>>>(Wout, bout, hfinal, out);
}

// Round 5
// 1992.351 us; speedup vs baseline: 1.5069x; 1.1006x over previous
//
#include <hip/hip_runtime.h>
#include <cstdint>
#include <cstddef>

#define EMB    512
#define HID    512
#define NCLASS 50257
#define BATCH  64
#define STEPS  256
#define FOURH  2048

typedef __attribute__((ext_vector_type(8))) short    bf16x8;
typedef __attribute__((ext_vector_type(4))) float    f32x4;
typedef __attribute__((ext_vector_type(8))) _Float16 h8v;

__device__ __forceinline__ unsigned short f2bf(float f) {
    union { float f; unsigned int u; } v; v.f = f;
    unsigned int u = v.u;
    return (unsigned short)((u + 0x7fffu + ((u >> 16) & 1u)) >> 16);
}

// ---------------- prep kernels ----------------

__global__ void k_bias(const float* __restrict__ bi, const float* __restrict__ bh,
                       float* __restrict__ bias) {
    int i = blockIdx.x * 256 + threadIdx.x;
    if (i < FOURH) bias[i] = bi[i] + bh[i];
}

// Wi [512][2048] fp32 -> WiT [2048][512] bf16
__global__ void k_wit(const float* __restrict__ Wi, unsigned short* __restrict__ WiT) {
    int n = blockIdx.x;
    int l = threadIdx.x;
    int k0 = l * 8;
    unsigned short t[8];
#pragma unroll
    for (int i = 0; i < 8; i++)
        t[i] = f2bf(Wi[(size_t)(k0 + i) * FOURH + n]);
    uint4 v;
    v.x = (unsigned)t[0] | ((unsigned)t[1] << 16);
    v.y = (unsigned)t[2] | ((unsigned)t[3] << 16);
    v.z = (unsigned)t[4] | ((unsigned)t[5] << 16);
    v.w = (unsigned)t[6] | ((unsigned)t[7] << 16);
    *(uint4*)(WiT + (size_t)n * EMB + k0) = v;
}

// Wh [512][2048] fp32 -> WhP [64 bid][32 c][512 k] fp16
// packed col c <-> (unit_local = (c>>4)*4 + ((c>>2)&3), gate = c&3)
// so lane (ct,quad) acc regs r=0..3 are gates i,f,g,o of unit ct*4+quad.
__global__ void k_whP(const float* __restrict__ Wh, _Float16* __restrict__ WhP) {
    int idx = blockIdx.x;            // 0..2047 = bid*32 + c
    int bidb = idx >> 5, c = idx & 31;
    int ul   = ((c >> 4) << 2) + ((c >> 2) & 3);
    int gate = c & 3;
    int gcol = gate * 512 + bidb * 8 + ul;
    int k0 = threadIdx.x * 8;
    h8v r;
#pragma unroll
    for (int i = 0; i < 8; i++)
        r[i] = (_Float16)Wh[(size_t)(k0 + i) * FOURH + gcol];
    *(h8v*)(WhP + (size_t)idx * 512 + k0) = r;
}

// XA[m][k] = bf16(emb[X[b][t]][k]),  m = t*64 + b
__global__ void k_gather(const int* __restrict__ X, const float* __restrict__ emb,
                         unsigned short* __restrict__ XA) {
    int chunk = blockIdx.x * 256 + threadIdx.x;
    int m  = chunk >> 6;
    int c8 = (chunk & 63) * 8;
    int t = m >> 6, b = m & 63;
    int row = X[b * STEPS + t];
    const float4* src = (const float4*)(emb + (size_t)row * EMB + c8);
    float4 f0 = src[0], f1 = src[1];
    uint4 v;
    v.x = (unsigned)f2bf(f0.x) | ((unsigned)f2bf(f0.y) << 16);
    v.y = (unsigned)f2bf(f0.z) | ((unsigned)f2bf(f0.w) << 16);
    v.z = (unsigned)f2bf(f1.x) | ((unsigned)f2bf(f1.y) << 16);
    v.w = (unsigned)f2bf(f1.z) | ((unsigned)f2bf(f1.w) << 16);
    *(uint4*)(XA + (size_t)m * EMB + c8) = v;
}

__global__ void k_zero(int* __restrict__ p, int n) {
    int i = blockIdx.x * 256 + threadIdx.x;
    if (i < n) p[i] = 0;
}

// ---------------- K1: XWT[t][col][b] = (XA @ Wi)^T + (bi+bh) ----------------
__global__ __launch_bounds__(256) void k_gemm1(const unsigned short* __restrict__ XA,
                                               const unsigned short* __restrict__ WiT,
                                               const float* __restrict__ bias,
                                               float* __restrict__ XWT) {
    __shared__ unsigned short Al[64 * 48];
    __shared__ unsigned short Bl[64 * 48];
    const int t  = blockIdx.y;
    const int m0 = t * 64;
    const int n0 = blockIdx.x * 64;
    const int tid  = threadIdx.x;
    const int w    = tid >> 6;
    const int lane = tid & 63;
    const int quad = lane >> 4;
    const int l16  = lane & 15;
    const int ar = tid >> 2;
    const int ac = (tid & 3) * 8;

    f32x4 acc[4];
#pragma unroll
    for (int i = 0; i < 4; i++) acc[i] = (f32x4){0.f, 0.f, 0.f, 0.f};

    for (int kk = 0; kk < 16; kk++) {
        const int k0 = kk * 32;
        __syncthreads();
        *(uint4*)(&Al[ar * 48 + ac]) = *(const uint4*)(XA  + (size_t)(m0 + ar) * EMB + k0 + ac);
        *(uint4*)(&Bl[ar * 48 + ac]) = *(const uint4*)(WiT + (size_t)(n0 + ar) * EMB + k0 + ac);
        __syncthreads();
        bf16x8 afrag = *(const bf16x8*)(&Bl[(w * 16 + l16) * 48 + quad * 8]);
#pragma unroll
        for (int mt = 0; mt < 4; mt++) {
            bf16x8 bfrag = *(const bf16x8*)(&Al[(mt * 16 + l16) * 48 + quad * 8]);
            acc[mt] = __builtin_amdgcn_mfma_f32_16x16x32_bf16(afrag, bfrag, acc[mt], 0, 0, 0);
        }
    }
    float bv[4];
#pragma unroll
    for (int r = 0; r < 4; r++) bv[r] = bias[n0 + w * 16 + quad * 4 + r];
#pragma unroll
    for (int mt = 0; mt < 4; mt++)
#pragma unroll
        for (int r = 0; r < 4; r++)
            XWT[((size_t)t * FOURH + n0 + w * 16 + quad * 4 + r) * 64 + mt * 16 + l16]
                = acc[mt][r] + bv[r];
}

// ---------------- K2: persistent LSTM recurrence, barrier-free waves ----------
// 64 blocks x 512 thr (8 waves). Block owns units bid*8..+7 (32 packed cols).
// Wave (ct,bt): lane (quad,l16) -> unit u=ct*4+quad, batch b=bt*16+l16;
// acc regs = gates i,f,g,o; c-state in 1 VGPR; Wh in 16 persistent A-frags.
// ZERO __syncthreads in the step loop and ZERO cache-maintenance ops:
//  - h traffic is exclusively MALL-coherent: stores = relaxed agent atomics
//    (8B, write-through), loads = global_load_dwordx4 sc0 sc1 (16B bypass).
//    L2 never holds an h line -> no invalidate needed, ever.
//  - LDS pack region is WAVE-PRIVATE (wave writes/reads only its own (u,b)
//    range) -> wave-local lgkmcnt(0) replaces block barriers.
//  - block completion via monotonic LDS counter; 8th wave raises flag(t+1).
//  - every wave polls all 64 flags itself (lane<->flag 1:1, relaxed).
// Race-freedom: flag(B)=t implies all B's waves consumed h(t-1) (data dep:
// loads -> gates -> LDS -> store -> vmcnt -> counter), so buffer (t+1)&1
// (holding h(t-1)) is rewritten only after every block passed poll(t).
__global__ __launch_bounds__(512, 1) void k_rnn(const float* __restrict__ XWT,
                                                const _Float16* __restrict__ WhP,
                                                _Float16* __restrict__ hG,
                                                float* __restrict__ hfinal,
                                                unsigned int* __restrict__ flags) {
    __shared__ _Float16 hw[64 * 8];   // wave-private pack regions
    __shared__ unsigned wcnt;         // monotonic wave-completion counter

    const int tid  = threadIdx.x;
    const int bid  = blockIdx.x;
    const int lane = tid & 63;
    const int wid  = tid >> 6;
    const int quad = lane >> 4;
    const int l16  = lane & 15;
    const int ct   = wid >> 2;
    const int bt   = wid & 3;
    const int u    = ct * 4 + quad;       // unit-local 0..7
    const int b    = bt * 16 + l16;       // batch 0..63

    if (tid == 0) wcnt = 0;
    __syncthreads();   // once, before the loop

    // persistent Wh A-fragments: lane holds WhP[bid][ct*16+l16][kk*32+quad*8 ..+7]
    h8v afrag[16];
    const _Float16* wsrc = WhP + ((size_t)(bid * 32 + ct * 16 + l16)) * 512 + quad * 8;
#pragma unroll
    for (int kk = 0; kk < 16; kk++) afrag[kk] = *(const h8v*)(wsrc + kk * 32);

    float c_state = 0.f;
    const size_t xwoff = (size_t)(bid * 8 + u) * 64 + b;

    // preload xw for t=0
    float xw0, xw1, xw2, xw3;
    {
        const float* xp = XWT + xwoff;
        xw0 = xp[0]; xw1 = xp[32768]; xw2 = xp[65536]; xw3 = xp[98304];
    }

    for (int t = 0; t < STEPS; t++) {
        // ---- wait for h(t): all 64 block flags >= t (t=0 passes at once) ----
        {
            const unsigned tgt = (unsigned)t;
            unsigned guard = 0;
            unsigned v = __hip_atomic_load(&flags[lane * 16],
                                           __ATOMIC_RELAXED, __HIP_MEMORY_SCOPE_AGENT);
            while (!__all(v >= tgt)) {
                __builtin_amdgcn_s_sleep(1);
                if (++guard > (1u << 17)) break;   // bailout: wrong answer, not hang
                v = __hip_atomic_load(&flags[lane * 16],
                                      __ATOMIC_RELAXED, __HIP_MEMORY_SCOPE_AGENT);
            }
        }

        // ---- load h(t) B-fragments: 16x 16B cache-bypass loads (MALL-fresh) ----
        const char* hsrc = (const char*)hG + (size_t)(t & 1) * 65536
                         + (size_t)b * 1024 + quad * 16;
        uint4 qv[16];
#pragma unroll
        for (int kk = 0; kk < 16; kk++)
            asm volatile("global_load_dwordx4 %0, %1, off sc0 sc1"
                         : "=v"(qv[kk]) : "v"(hsrc + kk * 64));
        asm volatile("s_waitcnt vmcnt(0)" ::: "memory");
        __builtin_amdgcn_sched_barrier(0);   // rule #18: pin MFMA below the wait

        f32x4 acc0 = {0.f, 0.f, 0.f, 0.f};
        f32x4 acc1 = {0.f, 0.f, 0.f, 0.f};
#pragma unroll
        for (int kk = 0; kk < 16; kk += 2) {
            union { uint4 q; h8v v; } f0, f1;
            f0.q = qv[kk]; f1.q = qv[kk + 1];
            acc0 = __builtin_amdgcn_mfma_f32_16x16x32_f16(afrag[kk],     f0.v, acc0, 0, 0, 0);
            acc1 = __builtin_amdgcn_mfma_f32_16x16x32_f16(afrag[kk + 1], f1.v, acc1, 0, 0, 0);
        }
        f32x4 acc = acc0 + acc1;

        float pre0 = acc[0] + xw0;
        float pre1 = acc[1] + xw1;
        float pre2 = acc[2] + xw2;
        float pre3 = acc[3] + xw3;
        float is = 1.f / (1.f + __expf(-pre0));
        float fs = 1.f / (1.f + __expf(-pre1));
        float gt = tanhf(pre2);
        float os = 1.f / (1.f + __expf(-pre3));
        c_state = fs * c_state + is * gt;
        float hnew = os * tanhf(c_state);

        if (t == STEPS - 1) {
            hfinal[(size_t)b * HID + bid * 8 + u] = hnew;
            break;   // kernel boundary publishes hfinal to k_out
        }

        // ---- wave-private pack: LDS write -> wave-local wait -> 8B read ----
        hw[b * 8 + u] = (_Float16)hnew;
        asm volatile("s_waitcnt lgkmcnt(0)" ::: "memory");
        if (quad == 0) {   // 16 lanes: batch b, units ct*4..ct*4+3 (8B)
            unsigned long long g = *(const unsigned long long*)(hw + b * 8 + ct * 4);
            unsigned long long* dst = (unsigned long long*)((char*)hG
                + (size_t)((t + 1) & 1) * 65536 + (size_t)b * 1024 + bid * 16 + ct * 8);
            __hip_atomic_store(dst, g, __ATOMIC_RELAXED, __HIP_MEMORY_SCOPE_AGENT);
        }
        asm volatile("s_waitcnt vmcnt(0)" ::: "memory");   // wave's h stores acked
        if (lane == 0) {
            unsigned old = atomicAdd(&wcnt, 1u);           // monotonic, no reset
            if (old == (unsigned)(8 * t + 7))              // last of 8 waves
                __hip_atomic_store(&flags[bid * 16], (unsigned)(t + 1),
                                   __ATOMIC_RELAXED, __HIP_MEMORY_SCOPE_AGENT);
        }

        // ---- prefetch xw(t+1): plain loads, complete under next poll ----
        {
            const float* xp = XWT + (size_t)(t + 1) * (FOURH * 64) + xwoff;
            xw0 = xp[0]; xw1 = xp[32768]; xw2 = xp[65536]; xw3 = xp[98304];
            asm volatile("" :: "v"(xw0), "v"(xw1), "v"(xw2), "v"(xw3));
        }
    }
}

// ---------------- K3: out = h @ Wout^T + bout ----------------
__global__ __launch_bounds__(128) void k_out(const float* __restrict__ Wout,
                                             const float* __restrict__ bout,
                                             const float* __restrict__ hfinal,
                                             float* __restrict__ out) {
    __shared__ float hl[BATCH * 128];
    const int tid = threadIdx.x;
    const int n = blockIdx.x * 128 + tid;
    const bool valid = n < NCLASS;
    float acc[BATCH];
#pragma unroll
    for (int b = 0; b < BATCH; b++) acc[b] = 0.f;
    const float4* W4 = (const float4*)Wout;
    const float4* h4 = (const float4*)hfinal;
    float4* hl4 = (float4*)hl;

    for (int kq = 0; kq < 4; kq++) {
        __syncthreads();
#pragma unroll
        for (int i = 0; i < 16; i++) {
            int f = i * 128 + tid;
            int b = f >> 5, kk = f & 31;
            hl4[f] = h4[b * 128 + kq * 32 + kk];
        }
        __syncthreads();
        if (valid) {
            for (int kk = 0; kk < 32; kk++) {
                float4 wv = W4[(size_t)n * 128 + kq * 32 + kk];
#pragma unroll
                for (int b = 0; b < BATCH; b++) {
                    float4 hv = hl4[b * 32 + kk];
                    acc[b] = fmaf(wv.x, hv.x, acc[b]);
                    acc[b] = fmaf(wv.y, hv.y, acc[b]);
                    acc[b] = fmaf(wv.z, hv.z, acc[b]);
                    acc[b] = fmaf(wv.w, hv.w, acc[b]);
                }
            }
        }
    }
    if (valid) {
        float bv = bout[n];
        for (int b = 0; b < BATCH; b++)
            out[(size_t)b * NCLASS + n] = acc[b] + bv;
    }
}

// ---------------- launch ----------------

extern "C" void kernel_launch(void* const* d_in, const int* in_sizes, int n_in,
                              void* d_out, int out_size, void* d_ws, size_t ws_size,
                              hipStream_t stream) {
    const int*   X    = (const int*)  d_in[0];
    const float* emb  = (const float*)d_in[1];
    const float* Wi   = (const float*)d_in[2];
    const float* Wh   = (const float*)d_in[3];
    const float* bi   = (const float*)d_in[4];
    const float* bh   = (const float*)d_in[5];
    const float* Wout = (const float*)d_in[10];
    const float* bout = (const float*)d_in[11];
    float* out = (float*)d_out;

    char* w = (char*)d_ws;
    float*          XWT    = (float*)(w);                           // 134217728 B
    unsigned short* XA     = (unsigned short*)(w + 134217728);      //  16777216 B (K1 only)
    // hG/flags aliased into XA tail — zeroed AFTER k_gemm1 consumed XA:
    _Float16*       hG     = (_Float16*)(w + 150732800);            //    131072 B (2 bufs)
    unsigned int*   flags  = (unsigned int*)(w + 150863872);        //      4096 B (64 x 64B)
    unsigned short* WiT    = (unsigned short*)(w + 150994944);      //   2097152 B
    _Float16*       WhP    = (_Float16*)(w + 153092096);            //   2097152 B
    float*          bias   = (float*)(w + 155189248);               //      8192 B
    float*          hfinal = (float*)(w + 155197440);               //    131072 B

    k_bias  <<<8,    256, 0, stream>>>(bi, bh, bias);
    k_wit   <<<2048,  64, 0, stream>>>(Wi, WiT);
    k_whP   <<<2048,  64, 0, stream>>>(Wh, WhP);
    k_gather<<<4096, 256, 0, stream>>>(X, emb, XA);
    k_gemm1 <<<dim3(32, 256), 256, 0, stream>>>(XA, WiT, bias, XWT);
    k_zero  <<<132,  256, 0, stream>>>((int*)hG, 33792);            // hG both bufs + flags

    k_rnn   <<<64,   512, 0, stream>>>(XWT, WhP, hG, hfinal, flags);

    k_out   <<<393,  128, 0, stream>>>(Wout, bout, hfinal, out);
}

// Round 7
// 1877.084 us; speedup vs baseline: 1.5994x; 1.0614x over previous
//
#include <hip/hip_runtime.h>
#include <cstdint>
#include <cstddef>

#define EMB    512
#define HID    512
#define NCLASS 50257
#define BATCH  64
#define STEPS  256
#define FOURH  2048
#define NBLK   64     // k_rnn grid

typedef __attribute__((ext_vector_type(8))) short    bf16x8;
typedef __attribute__((ext_vector_type(4))) float    f32x4;
typedef __attribute__((ext_vector_type(8))) _Float16 h8v;

__device__ __forceinline__ unsigned short f2bf(float f) {
    union { float f; unsigned int u; } v; v.f = f;
    unsigned int u = v.u;
    return (unsigned short)((u + 0x7fffu + ((u >> 16) & 1u)) >> 16);
}

// ---------------- prep kernels ----------------

__global__ void k_bias(const float* __restrict__ bi, const float* __restrict__ bh,
                       float* __restrict__ bias) {
    int i = blockIdx.x * 256 + threadIdx.x;
    if (i < FOURH) bias[i] = bi[i] + bh[i];
}

// Wi [512][2048] fp32 -> WiT [2048][512] bf16
__global__ void k_wit(const float* __restrict__ Wi, unsigned short* __restrict__ WiT) {
    int n = blockIdx.x;
    int l = threadIdx.x;
    int k0 = l * 8;
    unsigned short t[8];
#pragma unroll
    for (int i = 0; i < 8; i++)
        t[i] = f2bf(Wi[(size_t)(k0 + i) * FOURH + n]);
    uint4 v;
    v.x = (unsigned)t[0] | ((unsigned)t[1] << 16);
    v.y = (unsigned)t[2] | ((unsigned)t[3] << 16);
    v.z = (unsigned)t[4] | ((unsigned)t[5] << 16);
    v.w = (unsigned)t[6] | ((unsigned)t[7] << 16);
    *(uint4*)(WiT + (size_t)n * EMB + k0) = v;
}

// Wh [512][2048] fp32 -> WhP [64 bid][32 c][512 k] fp16
// packed col c <-> (unit_local = (c>>4)*4 + ((c>>2)&3), gate = c&3)
// so lane (tile,quad) acc regs r=0..3 are gates i,f,g,o of unit tile*4+quad.
__global__ void k_whP(const float* __restrict__ Wh, _Float16* __restrict__ WhP) {
    int idx = blockIdx.x;            // 0..2047 = bid*32 + c
    int bidb = idx >> 5, c = idx & 31;
    int ul   = ((c >> 4) << 2) + ((c >> 2) & 3);
    int gate = c & 3;
    int gcol = gate * 512 + bidb * 8 + ul;
    int k0 = threadIdx.x * 8;
    h8v r;
#pragma unroll
    for (int i = 0; i < 8; i++)
        r[i] = (_Float16)Wh[(size_t)(k0 + i) * FOURH + gcol];
    *(h8v*)(WhP + (size_t)idx * 512 + k0) = r;
}

// XA[m][k] = bf16(emb[X[b][t]][k]),  m = t*64 + b
__global__ void k_gather(const int* __restrict__ X, const float* __restrict__ emb,
                         unsigned short* __restrict__ XA) {
    int chunk = blockIdx.x * 256 + threadIdx.x;
    int m  = chunk >> 6;
    int c8 = (chunk & 63) * 8;
    int t = m >> 6, b = m & 63;
    int row = X[b * STEPS + t];
    const float4* src = (const float4*)(emb + (size_t)row * EMB + c8);
    float4 f0 = src[0], f1 = src[1];
    uint4 v;
    v.x = (unsigned)f2bf(f0.x) | ((unsigned)f2bf(f0.y) << 16);
    v.y = (unsigned)f2bf(f0.z) | ((unsigned)f2bf(f0.w) << 16);
    v.z = (unsigned)f2bf(f1.x) | ((unsigned)f2bf(f1.y) << 16);
    v.w = (unsigned)f2bf(f1.z) | ((unsigned)f2bf(f1.w) << 16);
    *(uint4*)(XA + (size_t)m * EMB + c8) = v;
}

__global__ void k_zero(int* __restrict__ p, int n) {
    int i = blockIdx.x * 256 + threadIdx.x;
    if (i < n) p[i] = 0;
}

// ---------------- K1: XWT[t][col][b] = (XA @ Wi)^T + (bi+bh) ----------------
__global__ __launch_bounds__(256) void k_gemm1(const unsigned short* __restrict__ XA,
                                               const unsigned short* __restrict__ WiT,
                                               const float* __restrict__ bias,
                                               float* __restrict__ XWT) {
    __shared__ unsigned short Al[64 * 48];
    __shared__ unsigned short Bl[64 * 48];
    const int t  = blockIdx.y;
    const int m0 = t * 64;
    const int n0 = blockIdx.x * 64;
    const int tid  = threadIdx.x;
    const int w    = tid >> 6;
    const int lane = tid & 63;
    const int quad = lane >> 4;
    const int l16  = lane & 15;
    const int ar = tid >> 2;
    const int ac = (tid & 3) * 8;

    f32x4 acc[4];
#pragma unroll
    for (int i = 0; i < 4; i++) acc[i] = (f32x4){0.f, 0.f, 0.f, 0.f};

    for (int kk = 0; kk < 16; kk++) {
        const int k0 = kk * 32;
        __syncthreads();
        *(uint4*)(&Al[ar * 48 + ac]) = *(const uint4*)(XA  + (size_t)(m0 + ar) * EMB + k0 + ac);
        *(uint4*)(&Bl[ar * 48 + ac]) = *(const uint4*)(WiT + (size_t)(n0 + ar) * EMB + k0 + ac);
        __syncthreads();
        bf16x8 afrag = *(const bf16x8*)(&Bl[(w * 16 + l16) * 48 + quad * 8]);
#pragma unroll
        for (int mt = 0; mt < 4; mt++) {
            bf16x8 bfrag = *(const bf16x8*)(&Al[(mt * 16 + l16) * 48 + quad * 8]);
            acc[mt] = __builtin_amdgcn_mfma_f32_16x16x32_bf16(afrag, bfrag, acc[mt], 0, 0, 0);
        }
    }
    float bv[4];
#pragma unroll
    for (int r = 0; r < 4; r++) bv[r] = bias[n0 + w * 16 + quad * 4 + r];
#pragma unroll
    for (int mt = 0; mt < 4; mt++)
#pragma unroll
        for (int r = 0; r < 4; r++)
            XWT[((size_t)t * FOURH + n0 + w * 16 + quad * 4 + r) * 64 + mt * 16 + l16]
                = acc[mt][r] + bv[r];
}

// ---------------- K2: persistent LSTM recurrence, epoch-counter sync ----------
// 64 blocks x 256 thr (4 waves). Block owns units bid*8..+7 (32 packed cols).
// Wave = bt (batch group); lane (quad,l16): batch b=bt*16+l16, computes BOTH
// 16-col tiles (units quad and quad+4) with a SHARED B-fragment set -> h read
// traffic halved vs r5, and 2x2 independent MFMA chains.
// Sync (r5 post-mortem: 64-flag all-lane polling = 32768 distinct-line MALL
// requests per poll round -> congestion was the step cost):
//  - ONE global epoch counter; each block's last wave does one relaxed agent
//    fetch_add after its vmcnt(0)-acked h-stores (LDS wcnt picks the last).
//  - pollers: whole waves load the SAME address (coalesces to 1 line request
//    per wave per round) until ectr >= 64*t. 256 same-line requests/round.
//  - h traffic stays exclusively MALL-coherent: loads = dwordx4 sc0 sc1
//    bypass; stores = relaxed agent 8B atomics (write-through). L2 never
//    holds an h line -> zero cache-maintenance ops, zero __syncthreads.
// Race-freedom: ectr >= 64*t implies every block published h(t), which (by
// data dependency load->mfma->gates->store->vmcnt->add) implies every block
// consumed h(t-1); buffer (t+1)&1 holds h(t-1), so publishing h(t+1) after
// poll(64*t) passes is safe. Readers of h(t) are protected one step later.
__global__ __launch_bounds__(256, 1) void k_rnn(const float* __restrict__ XWT,
                                                const _Float16* __restrict__ WhP,
                                                _Float16* __restrict__ hG,
                                                float* __restrict__ hfinal,
                                                unsigned int* __restrict__ flags) {
    __shared__ _Float16 hw[64 * 8];   // wave-private pack regions (by batch row)
    __shared__ unsigned wcnt;         // monotonic wave-completion counter

    const int tid  = threadIdx.x;
    const int bid  = blockIdx.x;
    const int lane = tid & 63;
    const int bt   = tid >> 6;            // wave id 0..3
    const int quad = lane >> 4;
    const int l16  = lane & 15;
    const int b    = bt * 16 + l16;       // batch 0..63

    if (tid == 0) wcnt = 0;
    __syncthreads();   // once, before the loop

    // persistent Wh A-fragments, both tiles:
    // afrag[tt][kk] = WhP[bid][tt*16+l16][kk*32+quad*8 ..+7]
    h8v afrag[2][16];
#pragma unroll
    for (int tt = 0; tt < 2; tt++) {
        const _Float16* wsrc = WhP + ((size_t)(bid * 32 + tt * 16 + l16)) * 512 + quad * 8;
#pragma unroll
        for (int kk = 0; kk < 16; kk++) afrag[tt][kk] = *(const h8v*)(wsrc + kk * 32);
    }

    float c0 = 0.f, c1 = 0.f;
    const size_t xwo0 = (size_t)(bid * 8 + quad) * 64 + b;       // tile0 unit
    const size_t xwo1 = (size_t)(bid * 8 + 4 + quad) * 64 + b;   // tile1 unit
    unsigned int* ectr = flags;          // single epoch counter (zeroed)

    // preload xw for t=0 (4 gates x 2 units)
    float xwA[4], xwB[4];
#pragma unroll
    for (int g = 0; g < 4; g++) {
        xwA[g] = XWT[(size_t)g * 32768 + xwo0];
        xwB[g] = XWT[(size_t)g * 32768 + xwo1];
    }

    for (int t = 0; t < STEPS; t++) {
        // ---- wait for h(t): epoch counter reaches 64*t (t=0 passes) ----
        {
            const unsigned tgt = (unsigned)(NBLK * t);
            unsigned guard = 0;
            unsigned v = __hip_atomic_load(ectr, __ATOMIC_RELAXED,
                                           __HIP_MEMORY_SCOPE_AGENT);
            while (v < tgt) {
                __builtin_amdgcn_s_sleep(1);
                if (++guard > (1u << 17)) break;   // bailout: wrong answer, not hang
                v = __hip_atomic_load(ectr, __ATOMIC_RELAXED,
                                      __HIP_MEMORY_SCOPE_AGENT);
            }
        }

        // ---- load h(t) B-fragments: 16x 16B cache-bypass loads (MALL-fresh) ----
        const char* hsrc = (const char*)hG + (size_t)(t & 1) * 65536
                         + (size_t)b * 1024 + quad * 16;
        uint4 qv[16];
#pragma unroll
        for (int kk = 0; kk < 16; kk++)
            asm volatile("global_load_dwordx4 %0, %1, off sc0 sc1"
                         : "=v"(qv[kk]) : "v"(hsrc + kk * 64));
        asm volatile("s_waitcnt vmcnt(0)" ::: "memory");
        __builtin_amdgcn_sched_barrier(0);   // rule #18: pin MFMA below the wait

        f32x4 aA0 = {0.f,0.f,0.f,0.f}, aA1 = {0.f,0.f,0.f,0.f};
        f32x4 aB0 = {0.f,0.f,0.f,0.f}, aB1 = {0.f,0.f,0.f,0.f};
#pragma unroll
        for (int kk = 0; kk < 16; kk += 2) {
            union { uint4 q; h8v v; } f0, f1;
            f0.q = qv[kk]; f1.q = qv[kk + 1];
            aA0 = __builtin_amdgcn_mfma_f32_16x16x32_f16(afrag[0][kk],     f0.v, aA0, 0, 0, 0);
            aB0 = __builtin_amdgcn_mfma_f32_16x16x32_f16(afrag[1][kk],     f0.v, aB0, 0, 0, 0);
            aA1 = __builtin_amdgcn_mfma_f32_16x16x32_f16(afrag[0][kk + 1], f1.v, aA1, 0, 0, 0);
            aB1 = __builtin_amdgcn_mfma_f32_16x16x32_f16(afrag[1][kk + 1], f1.v, aB1, 0, 0, 0);
        }
        f32x4 accA = aA0 + aA1;
        f32x4 accB = aB0 + aB1;

        // gates, tile0 (unit quad) and tile1 (unit quad+4)
        float iA = 1.f / (1.f + __expf(-(accA[0] + xwA[0])));
        float fA = 1.f / (1.f + __expf(-(accA[1] + xwA[1])));
        float gA = tanhf(accA[2] + xwA[2]);
        float oA = 1.f / (1.f + __expf(-(accA[3] + xwA[3])));
        c0 = fA * c0 + iA * gA;
        float hnA = oA * tanhf(c0);

        float iB = 1.f / (1.f + __expf(-(accB[0] + xwB[0])));
        float fB = 1.f / (1.f + __expf(-(accB[1] + xwB[1])));
        float gB = tanhf(accB[2] + xwB[2]);
        float oB = 1.f / (1.f + __expf(-(accB[3] + xwB[3])));
        c1 = fB * c1 + iB * gB;
        float hnB = oB * tanhf(c1);

        if (t == STEPS - 1) {
            hfinal[(size_t)b * HID + bid * 8 + quad]     = hnA;
            hfinal[(size_t)b * HID + bid * 8 + 4 + quad] = hnB;
            break;   // kernel boundary publishes hfinal to k_out
        }

        // ---- wave-private pack: LDS -> wave-local wait -> 2x8B MALL stores ----
        hw[b * 8 + quad]     = (_Float16)hnA;
        hw[b * 8 + 4 + quad] = (_Float16)hnB;
        asm volatile("s_waitcnt lgkmcnt(0)" ::: "memory");
        if (quad == 0) {   // 16 lanes: full 16B granule (units 0..7) of row b
            const unsigned long long* src = (const unsigned long long*)(hw + b * 8);
            unsigned long long lo = src[0], hi = src[1];
            unsigned long long* dst = (unsigned long long*)((char*)hG
                + (size_t)((t + 1) & 1) * 65536 + (size_t)b * 1024 + bid * 16);
            __hip_atomic_store(dst,     lo, __ATOMIC_RELAXED, __HIP_MEMORY_SCOPE_AGENT);
            __hip_atomic_store(dst + 1, hi, __ATOMIC_RELAXED, __HIP_MEMORY_SCOPE_AGENT);
        }
        asm volatile("s_waitcnt vmcnt(0)" ::: "memory");   // wave's h stores acked
        if (lane == 0) {
            unsigned old = atomicAdd(&wcnt, 1u);           // LDS, monotonic
            if (old == (unsigned)(4 * t + 3))              // last of 4 waves
                __hip_atomic_fetch_add(ectr, 1u, __ATOMIC_RELAXED,
                                       __HIP_MEMORY_SCOPE_AGENT);
        }

        // ---- prefetch xw(t+1): plain loads, complete under next poll ----
        {
            const float* xp = XWT + (size_t)(t + 1) * (FOURH * 64);
#pragma unroll
            for (int g = 0; g < 4; g++) {
                xwA[g] = xp[(size_t)g * 32768 + xwo0];
                xwB[g] = xp[(size_t)g * 32768 + xwo1];
            }
            asm volatile("" :: "v"(xwA[0]), "v"(xwA[1]), "v"(xwA[2]), "v"(xwA[3]),
                              "v"(xwB[0]), "v"(xwB[1]), "v"(xwB[2]), "v"(xwB[3]));
        }
    }
}

// ---------------- K3: out = h @ Wout^T + bout ----------------
__global__ __launch_bounds__(128) void k_out(const float* __restrict__ Wout,
                                             const float* __restrict__ bout,
                                             const float* __restrict__ hfinal,
                                             float* __restrict__ out) {
    __shared__ float hl[BATCH * 128];
    const int tid = threadIdx.x;
    const int n = blockIdx.x * 128 + tid;
    const bool valid = n < NCLASS;
    float acc[BATCH];
#pragma unroll
    for (int b = 0; b < BATCH; b++) acc[b] = 0.f;
    const float4* W4 = (const float4*)Wout;
    const float4* h4 = (const float4*)hfinal;
    float4* hl4 = (float4*)hl;

    for (int kq = 0; kq < 4; kq++) {
        __syncthreads();
#pragma unroll
        for (int i = 0; i < 16; i++) {
            int f = i * 128 + tid;
            int b = f >> 5, kk = f & 31;
            hl4[f] = h4[b * 128 + kq * 32 + kk];
        }
        __syncthreads();
        if (valid) {
            for (int kk = 0; kk < 32; kk++) {
                float4 wv = W4[(size_t)n * 128 + kq * 32 + kk];
#pragma unroll
                for (int b = 0; b < BATCH; b++) {
                    float4 hv = hl4[b * 32 + kk];
                    acc[b] = fmaf(wv.x, hv.x, acc[b]);
                    acc[b] = fmaf(wv.y, hv.y, acc[b]);
                    acc[b] = fmaf(wv.z, hv.z, acc[b]);
                    acc[b] = fmaf(wv.w, hv.w, acc[b]);
                }
            }
        }
    }
    if (valid) {
        float bv = bout[n];
        for (int b = 0; b < BATCH; b++)
            out[(size_t)b * NCLASS + n] = acc[b] + bv;
    }
}

// ---------------- launch ----------------

extern "C" void kernel_launch(void* const* d_in, const int* in_sizes, int n_in,
                              void* d_out, int out_size, void* d_ws, size_t ws_size,
                              hipStream_t stream) {
    const int*   X    = (const int*)  d_in[0];
    const float* emb  = (const float*)d_in[1];
    const float* Wi   = (const float*)d_in[2];
    const float* Wh   = (const float*)d_in[3];
    const float* bi   = (const float*)d_in[4];
    const float* bh   = (const float*)d_in[5];
    const float* Wout = (const float*)d_in[10];
    const float* bout = (const float*)d_in[11];
    float* out = (float*)d_out;

    char* w = (char*)d_ws;
    float*          XWT    = (float*)(w);                           // 134217728 B
    unsigned short* XA     = (unsigned short*)(w + 134217728);      //  16777216 B (K1 only)
    // hG/flags aliased into XA tail — zeroed AFTER k_gemm1 consumed XA:
    _Float16*       hG     = (_Float16*)(w + 150732800);            //    131072 B (2 bufs)
    unsigned int*   flags  = (unsigned int*)(w + 150863872);        //      4096 B (ectr)
    unsigned short* WiT    = (unsigned short*)(w + 150994944);      //   2097152 B
    _Float16*       WhP    = (_Float16*)(w + 153092096);            //   2097152 B
    float*          bias   = (float*)(w + 155189248);               //      8192 B
    float*          hfinal = (float*)(w + 155197440);               //    131072 B

    k_bias  <<<8,    256, 0, stream>>>(bi, bh, bias);
    k_wit   <<<2048,  64, 0, stream>>>(Wi, WiT);
    k_whP   <<<2048,  64, 0, stream>>>(Wh, WhP);
    k_gather<<<4096, 256, 0, stream>>>(X, emb, XA);
    k_gemm1 <<<dim3(32, 256), 256, 0, stream>>>(XA, WiT, bias, XWT);
    k_zero  <<<132,  256, 0, stream>>>((int*)hG, 33792);            // hG both bufs + ectr

    k_rnn   <<<NBLK, 256, 0, stream>>>(XWT, WhP, hG, hfinal, flags);

    k_out   <<<393,  128, 0, stream>>>(Wout, bout, hfinal, out);
}

// Round 8
// 1641.163 us; speedup vs baseline: 1.8293x; 1.1438x over previous
//
#include <hip/hip_runtime.h>
#include <cstdint>
#include <cstddef>

#define EMB    512
#define HID    512
#define NCLASS 50257
#define BATCH  64
#define STEPS  256
#define FOURH  2048
#define NBLK   64     // k_rnn grid

typedef __attribute__((ext_vector_type(8))) short    bf16x8;
typedef __attribute__((ext_vector_type(4))) float    f32x4;
typedef __attribute__((ext_vector_type(8))) _Float16 h8v;

__device__ __forceinline__ unsigned short f2bf(float f) {
    union { float f; unsigned int u; } v; v.f = f;
    unsigned int u = v.u;
    return (unsigned short)((u + 0x7fffu + ((u >> 16) & 1u)) >> 16);
}

// ---------------- prep kernels ----------------

__global__ void k_bias(const float* __restrict__ bi, const float* __restrict__ bh,
                       float* __restrict__ bias) {
    int i = blockIdx.x * 256 + threadIdx.x;
    if (i < FOURH) bias[i] = bi[i] + bh[i];
}

// Wi [512][2048] fp32 -> WiT [2048][512] bf16
__global__ void k_wit(const float* __restrict__ Wi, unsigned short* __restrict__ WiT) {
    int n = blockIdx.x;
    int l = threadIdx.x;
    int k0 = l * 8;
    unsigned short t[8];
#pragma unroll
    for (int i = 0; i < 8; i++)
        t[i] = f2bf(Wi[(size_t)(k0 + i) * FOURH + n]);
    uint4 v;
    v.x = (unsigned)t[0] | ((unsigned)t[1] << 16);
    v.y = (unsigned)t[2] | ((unsigned)t[3] << 16);
    v.z = (unsigned)t[4] | ((unsigned)t[5] << 16);
    v.w = (unsigned)t[6] | ((unsigned)t[7] << 16);
    *(uint4*)(WiT + (size_t)n * EMB + k0) = v;
}

// Wh [512][2048] fp32 -> WhP [64 bid][32 c][512 k] fp16
// packed col c <-> (unit_local = (c>>4)*4 + ((c>>2)&3), gate = c&3)
// so lane (tile,quad) acc regs r=0..3 are gates i,f,g,o of unit tile*4+quad.
__global__ void k_whP(const float* __restrict__ Wh, _Float16* __restrict__ WhP) {
    int idx = blockIdx.x;            // 0..2047 = bid*32 + c
    int bidb = idx >> 5, c = idx & 31;
    int ul   = ((c >> 4) << 2) + ((c >> 2) & 3);
    int gate = c & 3;
    int gcol = gate * 512 + bidb * 8 + ul;
    int k0 = threadIdx.x * 8;
    h8v r;
#pragma unroll
    for (int i = 0; i < 8; i++)
        r[i] = (_Float16)Wh[(size_t)(k0 + i) * FOURH + gcol];
    *(h8v*)(WhP + (size_t)idx * 512 + k0) = r;
}

// XA[m][k] = bf16(emb[X[b][t]][k]),  m = t*64 + b
__global__ void k_gather(const int* __restrict__ X, const float* __restrict__ emb,
                         unsigned short* __restrict__ XA) {
    int chunk = blockIdx.x * 256 + threadIdx.x;
    int m  = chunk >> 6;
    int c8 = (chunk & 63) * 8;
    int t = m >> 6, b = m & 63;
    int row = X[b * STEPS + t];
    const float4* src = (const float4*)(emb + (size_t)row * EMB + c8);
    float4 f0 = src[0], f1 = src[1];
    uint4 v;
    v.x = (unsigned)f2bf(f0.x) | ((unsigned)f2bf(f0.y) << 16);
    v.y = (unsigned)f2bf(f0.z) | ((unsigned)f2bf(f0.w) << 16);
    v.z = (unsigned)f2bf(f1.x) | ((unsigned)f2bf(f1.y) << 16);
    v.w = (unsigned)f2bf(f1.z) | ((unsigned)f2bf(f1.w) << 16);
    *(uint4*)(XA + (size_t)m * EMB + c8) = v;
}

__global__ void k_zero(int* __restrict__ p, int n) {
    int i = blockIdx.x * 256 + threadIdx.x;
    if (i < n) p[i] = 0;
}

// ---------------- K1: XWT[t][col][b] = (XA @ Wi)^T + (bi+bh) ----------------
__global__ __launch_bounds__(256) void k_gemm1(const unsigned short* __restrict__ XA,
                                               const unsigned short* __restrict__ WiT,
                                               const float* __restrict__ bias,
                                               float* __restrict__ XWT) {
    __shared__ unsigned short Al[64 * 48];
    __shared__ unsigned short Bl[64 * 48];
    const int t  = blockIdx.y;
    const int m0 = t * 64;
    const int n0 = blockIdx.x * 64;
    const int tid  = threadIdx.x;
    const int w    = tid >> 6;
    const int lane = tid & 63;
    const int quad = lane >> 4;
    const int l16  = lane & 15;
    const int ar = tid >> 2;
    const int ac = (tid & 3) * 8;

    f32x4 acc[4];
#pragma unroll
    for (int i = 0; i < 4; i++) acc[i] = (f32x4){0.f, 0.f, 0.f, 0.f};

    for (int kk = 0; kk < 16; kk++) {
        const int k0 = kk * 32;
        __syncthreads();
        *(uint4*)(&Al[ar * 48 + ac]) = *(const uint4*)(XA  + (size_t)(m0 + ar) * EMB + k0 + ac);
        *(uint4*)(&Bl[ar * 48 + ac]) = *(const uint4*)(WiT + (size_t)(n0 + ar) * EMB + k0 + ac);
        __syncthreads();
        bf16x8 afrag = *(const bf16x8*)(&Bl[(w * 16 + l16) * 48 + quad * 8]);
#pragma unroll
        for (int mt = 0; mt < 4; mt++) {
            bf16x8 bfrag = *(const bf16x8*)(&Al[(mt * 16 + l16) * 48 + quad * 8]);
            acc[mt] = __builtin_amdgcn_mfma_f32_16x16x32_bf16(afrag, bfrag, acc[mt], 0, 0, 0);
        }
    }
    float bv[4];
#pragma unroll
    for (int r = 0; r < 4; r++) bv[r] = bias[n0 + w * 16 + quad * 4 + r];
#pragma unroll
    for (int mt = 0; mt < 4; mt++)
#pragma unroll
        for (int r = 0; r < 4; r++)
            XWT[((size_t)t * FOURH + n0 + w * 16 + quad * 4 + r) * 64 + mt * 16 + l16]
                = acc[mt][r] + bv[r];
}

// ---------------- K2: persistent LSTM recurrence ------------------------------
// 64 blocks x 256 thr (4 waves). Block owns units bid*8..+7 (32 packed cols).
// Wave = bt (batch group); lane (quad,l16): batch b=bt*16+l16, computes BOTH
// 16-col tiles (units quad, quad+4) with a SHARED B-fragment set.
// Sync, v3 (r7 post-mortem: r5 = poll congestion ~4us [32768 distinct-line
// requests/round]; r7 = 64-deep SERIALIZED fetch_add RMW chain on one line
// ~4us. Fix = parallel stores AND cheap polling):
//  - per-block flag at its own 64B line, raised by a relaxed plain STORE
//    (no RMW -> 64 flag raises proceed in parallel at the MALL).
//  - ONE wave per block (bt==0) polls the 64 flags (lane<->flag, 64 waves x
//    64 lines = 64 same-line requests/round, far below saturation); waves
//    1-3 spin on an LDS epoch word (zero fabric traffic).
//  - h traffic stays exclusively MALL-coherent: loads = dwordx4 sc0 sc1
//    bypass; stores = relaxed agent 8B atomics. Zero cache-maintenance ops,
//    zero __syncthreads in the loop.
// Race-freedom: flag(B)>=t implies B published h(t), which (by data dep
// load->mfma->gates->store->vmcnt->LDS-count->flag) implies B consumed
// h(t-1); buffer (t+1)&1 holds h(t-1), so publishing h(t+1) after the gate
// for t passes is safe. LDS ep gate releases waves 1-3 only after the polling
// wave observed all flags; their sc-bypass loads issue after (data dep).
__global__ __launch_bounds__(256, 1) void k_rnn(const float* __restrict__ XWT,
                                                const _Float16* __restrict__ WhP,
                                                _Float16* __restrict__ hG,
                                                float* __restrict__ hfinal,
                                                unsigned int* __restrict__ flags) {
    __shared__ _Float16 hw[64 * 8];   // wave-private pack regions (by batch row)
    __shared__ unsigned wcnt;         // monotonic wave-completion counter
    __shared__ int      ep;           // LDS epoch gate (written by poller wave)

    const int tid  = threadIdx.x;
    const int bid  = blockIdx.x;
    const int lane = tid & 63;
    const int bt   = tid >> 6;            // wave id 0..3
    const int quad = lane >> 4;
    const int l16  = lane & 15;
    const int b    = bt * 16 + l16;       // batch 0..63

    if (tid == 0) { wcnt = 0; ep = 0; }
    __syncthreads();   // once, before the loop

    // persistent Wh A-fragments, both tiles:
    // afrag[tt][kk] = WhP[bid][tt*16+l16][kk*32+quad*8 ..+7]
    h8v afrag[2][16];
#pragma unroll
    for (int tt = 0; tt < 2; tt++) {
        const _Float16* wsrc = WhP + ((size_t)(bid * 32 + tt * 16 + l16)) * 512 + quad * 8;
#pragma unroll
        for (int kk = 0; kk < 16; kk++) afrag[tt][kk] = *(const h8v*)(wsrc + kk * 32);
    }

    float c0 = 0.f, c1 = 0.f;
    const size_t xwo0 = (size_t)(bid * 8 + quad) * 64 + b;       // tile0 unit
    const size_t xwo1 = (size_t)(bid * 8 + 4 + quad) * 64 + b;   // tile1 unit

    // preload xw for t=0 (4 gates x 2 units)
    float xwA[4], xwB[4];
#pragma unroll
    for (int g = 0; g < 4; g++) {
        xwA[g] = XWT[(size_t)g * 32768 + xwo0];
        xwB[g] = XWT[(size_t)g * 32768 + xwo1];
    }

    for (int t = 0; t < STEPS; t++) {
        // ---- gate for h(t): all 64 block flags >= t (t=0 passes at once) ----
        if (t > 0) {
            if (bt == 0) {   // poller wave: lane <-> flag, 64 distinct lines
                const unsigned tgt = (unsigned)t;
                unsigned guard = 0;
                unsigned v = __hip_atomic_load(&flags[lane * 16],
                                               __ATOMIC_RELAXED, __HIP_MEMORY_SCOPE_AGENT);
                while (!__all(v >= tgt)) {
                    __builtin_amdgcn_s_sleep(1);
                    if (++guard > (1u << 17)) break;   // bailout: wrong answer, not hang
                    v = __hip_atomic_load(&flags[lane * 16],
                                          __ATOMIC_RELAXED, __HIP_MEMORY_SCOPE_AGENT);
                }
                if (lane == 0) *(volatile int*)&ep = t;   // release waves 1-3
            } else {         // LDS spin: zero fabric traffic
                unsigned guard = 0;
                while (*(volatile int*)&ep < t) {
                    __builtin_amdgcn_s_sleep(1);
                    if (++guard > (1u << 20)) break;
                }
            }
        }

        // ---- load h(t) B-fragments: 16x 16B cache-bypass loads (MALL-fresh) ----
        const char* hsrc = (const char*)hG + (size_t)(t & 1) * 65536
                         + (size_t)b * 1024 + quad * 16;
        uint4 qv[16];
#pragma unroll
        for (int kk = 0; kk < 16; kk++)
            asm volatile("global_load_dwordx4 %0, %1, off sc0 sc1"
                         : "=v"(qv[kk]) : "v"(hsrc + kk * 64));
        asm volatile("s_waitcnt vmcnt(0)" ::: "memory");
        __builtin_amdgcn_sched_barrier(0);   // rule #18: pin MFMA below the wait

        f32x4 aA0 = {0.f,0.f,0.f,0.f}, aA1 = {0.f,0.f,0.f,0.f};
        f32x4 aB0 = {0.f,0.f,0.f,0.f}, aB1 = {0.f,0.f,0.f,0.f};
#pragma unroll
        for (int kk = 0; kk < 16; kk += 2) {
            union { uint4 q; h8v v; } f0, f1;
            f0.q = qv[kk]; f1.q = qv[kk + 1];
            aA0 = __builtin_amdgcn_mfma_f32_16x16x32_f16(afrag[0][kk],     f0.v, aA0, 0, 0, 0);
            aB0 = __builtin_amdgcn_mfma_f32_16x16x32_f16(afrag[1][kk],     f0.v, aB0, 0, 0, 0);
            aA1 = __builtin_amdgcn_mfma_f32_16x16x32_f16(afrag[0][kk + 1], f1.v, aA1, 0, 0, 0);
            aB1 = __builtin_amdgcn_mfma_f32_16x16x32_f16(afrag[1][kk + 1], f1.v, aB1, 0, 0, 0);
        }
        f32x4 accA = aA0 + aA1;
        f32x4 accB = aB0 + aB1;

        // gates, tile0 (unit quad) and tile1 (unit quad+4)
        float iA = 1.f / (1.f + __expf(-(accA[0] + xwA[0])));
        float fA = 1.f / (1.f + __expf(-(accA[1] + xwA[1])));
        float gA = tanhf(accA[2] + xwA[2]);
        float oA = 1.f / (1.f + __expf(-(accA[3] + xwA[3])));
        c0 = fA * c0 + iA * gA;
        float hnA = oA * tanhf(c0);

        float iB = 1.f / (1.f + __expf(-(accB[0] + xwB[0])));
        float fB = 1.f / (1.f + __expf(-(accB[1] + xwB[1])));
        float gB = tanhf(accB[2] + xwB[2]);
        float oB = 1.f / (1.f + __expf(-(accB[3] + xwB[3])));
        c1 = fB * c1 + iB * gB;
        float hnB = oB * tanhf(c1);

        if (t == STEPS - 1) {
            hfinal[(size_t)b * HID + bid * 8 + quad]     = hnA;
            hfinal[(size_t)b * HID + bid * 8 + 4 + quad] = hnB;
            break;   // kernel boundary publishes hfinal to k_out
        }

        // ---- wave-private pack: LDS -> wave-local wait -> 2x8B MALL stores ----
        hw[b * 8 + quad]     = (_Float16)hnA;
        hw[b * 8 + 4 + quad] = (_Float16)hnB;
        asm volatile("s_waitcnt lgkmcnt(0)" ::: "memory");
        if (quad == 0) {   // 16 lanes: full 16B granule (units 0..7) of row b
            const unsigned long long* src = (const unsigned long long*)(hw + b * 8);
            unsigned long long lo = src[0], hi = src[1];
            unsigned long long* dst = (unsigned long long*)((char*)hG
                + (size_t)((t + 1) & 1) * 65536 + (size_t)b * 1024 + bid * 16);
            __hip_atomic_store(dst,     lo, __ATOMIC_RELAXED, __HIP_MEMORY_SCOPE_AGENT);
            __hip_atomic_store(dst + 1, hi, __ATOMIC_RELAXED, __HIP_MEMORY_SCOPE_AGENT);
        }
        asm volatile("s_waitcnt vmcnt(0)" ::: "memory");   // wave's h stores acked
        if (lane == 0) {
            unsigned old = atomicAdd(&wcnt, 1u);           // LDS, monotonic
            if (old == (unsigned)(4 * t + 3))              // last of 4 waves:
                __hip_atomic_store(&flags[bid * 16], (unsigned)(t + 1),
                                   __ATOMIC_RELAXED, __HIP_MEMORY_SCOPE_AGENT);
        }

        // ---- prefetch xw(t+1): plain loads, complete under next gate ----
        {
            const float* xp = XWT + (size_t)(t + 1) * (FOURH * 64);
#pragma unroll
            for (int g = 0; g < 4; g++) {
                xwA[g] = xp[(size_t)g * 32768 + xwo0];
                xwB[g] = xp[(size_t)g * 32768 + xwo1];
            }
            asm volatile("" :: "v"(xwA[0]), "v"(xwA[1]), "v"(xwA[2]), "v"(xwA[3]),
                              "v"(xwB[0]), "v"(xwB[1]), "v"(xwB[2]), "v"(xwB[3]));
        }
    }
}

// ---------------- K3: out = h @ Wout^T + bout ----------------
__global__ __launch_bounds__(128) void k_out(const float* __restrict__ Wout,
                                             const float* __restrict__ bout,
                                             const float* __restrict__ hfinal,
                                             float* __restrict__ out) {
    __shared__ float hl[BATCH * 128];
    const int tid = threadIdx.x;
    const int n = blockIdx.x * 128 + tid;
    const bool valid = n < NCLASS;
    float acc[BATCH];
#pragma unroll
    for (int b = 0; b < BATCH; b++) acc[b] = 0.f;
    const float4* W4 = (const float4*)Wout;
    const float4* h4 = (const float4*)hfinal;
    float4* hl4 = (float4*)hl;

    for (int kq = 0; kq < 4; kq++) {
        __syncthreads();
#pragma unroll
        for (int i = 0; i < 16; i++) {
            int f = i * 128 + tid;
            int b = f >> 5, kk = f & 31;
            hl4[f] = h4[b * 128 + kq * 32 + kk];
        }
        __syncthreads();
        if (valid) {
            for (int kk = 0; kk < 32; kk++) {
                float4 wv = W4[(size_t)n * 128 + kq * 32 + kk];
#pragma unroll
                for (int b = 0; b < BATCH; b++) {
                    float4 hv = hl4[b * 32 + kk];
                    acc[b] = fmaf(wv.x, hv.x, acc[b]);
                    acc[b] = fmaf(wv.y, hv.y, acc[b]);
                    acc[b] = fmaf(wv.z, hv.z, acc[b]);
                    acc[b] = fmaf(wv.w, hv.w, acc[b]);
                }
            }
        }
    }
    if (valid) {
        float bv = bout[n];
        for (int b = 0; b < BATCH; b++)
            out[(size_t)b * NCLASS + n] = acc[b] + bv;
    }
}

// ---------------- launch ----------------

extern "C" void kernel_launch(void* const* d_in, const int* in_sizes, int n_in,
                              void* d_out, int out_size, void* d_ws, size_t ws_size,
                              hipStream_t stream) {
    const int*   X    = (const int*)  d_in[0];
    const float* emb  = (const float*)d_in[1];
    const float* Wi   = (const float*)d_in[2];
    const float* Wh   = (const float*)d_in[3];
    const float* bi   = (const float*)d_in[4];
    const float* bh   = (const float*)d_in[5];
    const float* Wout = (const float*)d_in[10];
    const float* bout = (const float*)d_in[11];
    float* out = (float*)d_out;

    char* w = (char*)d_ws;
    float*          XWT    = (float*)(w);                           // 134217728 B
    unsigned short* XA     = (unsigned short*)(w + 134217728);      //  16777216 B (K1 only)
    // hG/flags aliased into XA tail — zeroed AFTER k_gemm1 consumed XA:
    _Float16*       hG     = (_Float16*)(w + 150732800);            //    131072 B (2 bufs)
    unsigned int*   flags  = (unsigned int*)(w + 150863872);        //      4096 B (64 x 64B)
    unsigned short* WiT    = (unsigned short*)(w + 150994944);      //   2097152 B
    _Float16*       WhP    = (_Float16*)(w + 153092096);            //   2097152 B
    float*          bias   = (float*)(w + 155189248);               //      8192 B
    float*          hfinal = (float*)(w + 155197440);               //    131072 B

    k_bias  <<<8,    256, 0, stream>>>(bi, bh, bias);
    k_wit   <<<2048,  64, 0, stream>>>(Wi, WiT);
    k_whP   <<<2048,  64, 0, stream>>>(Wh, WhP);
    k_gather<<<4096, 256, 0, stream>>>(X, emb, XA);
    k_gemm1 <<<dim3(32, 256), 256, 0, stream>>>(XA, WiT, bias, XWT);
    k_zero  <<<132,  256, 0, stream>>>((int*)hG, 33792);            // hG both bufs + flags

    k_rnn   <<<NBLK, 256, 0, stream>>>(XWT, WhP, hG, hfinal, flags);

    k_out   <<<393,  128, 0, stream>>>(Wout, bout, hfinal, out);
}